// Round 3
// baseline (214.283 us; speedup 1.0000x reference)
//
#include <hip/hip_runtime.h>

#define B_  8
#define C_  128
#define H_  96
#define W_  160
#define HWp (H_ * W_)   // 15360 floats per channel plane

typedef short  short8  __attribute__((ext_vector_type(8)));
typedef float  floatx4 __attribute__((ext_vector_type(4)));
typedef float  f4      __attribute__((ext_vector_type(4)));

// round-to-nearest-even fp32 -> bf16, packed pair (a low 16, b high 16)
__device__ __forceinline__ unsigned pk_bf16(float a, float b) {
    unsigned ua = __float_as_uint(a);
    unsigned ub = __float_as_uint(b);
    ua = (ua + 0x7FFFu + ((ua >> 16) & 1u)) >> 16;
    ub = (ub + 0x7FFFu + ((ub >> 16) & 1u)) & 0xFFFF0000u;
    return ua | ub;
}

// Band-GEMM correlation:
//   out[b, dy*9+o, y, x] = (1/128) * sum_c one[b,c,y,x] * two[b,c,y+dy-4,x+o-4]
// Tile: 8y x 16x per block (512 thr, 8 waves; wave w = y-row w).
// LDS records: 16B = one lane's 8 bf16 (k = q*8+j), q-XOR swizzled position.
//   two_q: 17 rows x 129 recs (row ry: ty=y0-4+ry; rec = ct*64+q*16+(nloc^4q), word=P&3)
//   one_q:  8 rows x  65 recs
// Col-tile0: x2'=n (dx=n-m). Col-tile1 packs 2 dy per MFMA: cols = (dy half n>>3, x2'=16+(n&7)).
__global__ __launch_bounds__(512, 4)
void corr_kernel(const float* __restrict__ one, const float* __restrict__ two,
                 float* __restrict__ out) {
    __shared__ uint4 smem[2713];                 // 43,408 B (union with epilogue buffer)
    unsigned* smem_w = reinterpret_cast<unsigned*>(smem);
    float*    ep     = reinterpret_cast<float*>(smem);   // 81*8*16 = 10368 floats

    const int id = blockIdx.x;
    const int b  = id & 7;            // one batch per XCD
    const int jj = id >> 3;
    const int yt = jj % 12;
    const int xt = jj / 12;
    const int y0 = yt * 8;
    const int x0 = xt * 16;

    const int tid  = threadIdx.x;
    const int lane = tid & 63;
    const int w    = tid >> 6;        // wave id = y-row

    // ---- staging decode: c-pair tasks ----
    // two: (ry16, x4g8, P16) -> 2048 tasks = 4/thread
    const int t_x4g = tid & 7;
    const int t_P   = (tid >> 3) & 15;
    const int t_ry0 = tid >> 7;                    // ry = t_ry0 + 4i
    // one: (y8, x4g4, P16) -> 512 tasks = 1/thread
    const int o_x4g = tid & 3;
    const int o_P   = (tid >> 2) & 15;
    const int o_y   = tid >> 6;

    // two task pointers + validity (float4 spans never straddle the boundary:
    // gxb = x0-4+4*x4g is 4-aligned and W%4==0 -> full or none)
    const float* tp[4];
    bool tv[4];
    {
        const int gxb = x0 - 4 + 4 * t_x4g;
        #pragma unroll
        for (int i = 0; i < 4; ++i) {
            const int ry = t_ry0 + 4 * i;
            const int ty = y0 - 4 + ry;
            tv[i] = ((unsigned)ty < H_) && (gxb >= 0) && (gxb <= W_ - 4);
            tp[i] = two + ((b * C_ + 2 * t_P) * H_ + ty) * W_ + gxb;
        }
    }
    const float* op = one + ((b * C_ + 2 * o_P) * H_ + (y0 + o_y)) * W_ + (x0 + 4 * o_x4g);

    // write bases (word units)
    const int t_qq   = t_P >> 2;
    const int t_wsel = t_P & 3;
    const int t_ct   = t_x4g >> 2;
    const int t_nb   = 4 * (t_x4g & 3);            // nloc base
    const int o_qq   = o_P >> 2;
    const int o_wsel = o_P & 3;

    // fragment-read inner offsets (rec units)
    const int q   = lane >> 4;
    const int n   = lane & 15;
    const int inn = q * 16 + (n ^ (q << 2));              // ct0 & A inner
    const int in1 = 64 + q * 16 + ((n & 7) ^ (q << 2));   // ct1 inner
    const int nh  = n >> 3;                               // dy half for ct1

    floatx4 acc0[9], acc1[5];
    #pragma unroll
    for (int i = 0; i < 9; ++i) acc0[i] = floatx4{0.f, 0.f, 0.f, 0.f};
    #pragma unroll
    for (int i = 0; i < 5; ++i) acc1[i] = floatx4{0.f, 0.f, 0.f, 0.f};

    f4 rt[4][2], ro[2];

    // ---- prologue: zero junk row 16, issue loads for chunk 0 ----
    if (tid < 129) smem[16 * 129 + tid] = uint4{0u, 0u, 0u, 0u};
    #pragma unroll
    for (int i = 0; i < 4; ++i) {
        if (tv[i]) { rt[i][0] = *(const f4*)tp[i]; rt[i][1] = *(const f4*)(tp[i] + HWp); }
        else       { rt[i][0] = f4{0.f,0.f,0.f,0.f}; rt[i][1] = f4{0.f,0.f,0.f,0.f}; }
    }
    ro[0] = *(const f4*)op; ro[1] = *(const f4*)(op + HWp);

    #pragma unroll
    for (int ck = 0; ck < 4; ++ck) {
        // ---- commit raws -> LDS (b32 writes, q-XOR swizzled) ----
        #pragma unroll
        for (int i = 0; i < 4; ++i) {
            const int rbase = ((t_ry0 + 4 * i) * 129 + t_ct * 64 + t_qq * 16) * 4 + t_wsel;
            #pragma unroll
            for (int j = 0; j < 4; ++j) {
                const int pos = (t_nb + j) ^ (t_qq << 2);
                smem_w[rbase + pos * 4] = pk_bf16(rt[i][0][j], rt[i][1][j]);
            }
        }
        {
            const int rbase = (2193 + o_y * 65 + o_qq * 16) * 4 + o_wsel;
            #pragma unroll
            for (int j = 0; j < 4; ++j) {
                const int pos = (4 * o_x4g + j) ^ (o_qq << 2);
                smem_w[rbase + pos * 4] = pk_bf16(ro[0][j], ro[1][j]);
            }
        }
        __syncthreads();   // (A) staged data visible

        // ---- issue loads for chunk ck+1 (land during MFMA phase) ----
        if (ck < 3) {
            const int coff = (ck + 1) * 32 * HWp;
            #pragma unroll
            for (int i = 0; i < 4; ++i) {
                if (tv[i]) { rt[i][0] = *(const f4*)(tp[i] + coff); rt[i][1] = *(const f4*)(tp[i] + coff + HWp); }
                else       { rt[i][0] = f4{0.f,0.f,0.f,0.f}; rt[i][1] = f4{0.f,0.f,0.f,0.f}; }
            }
            ro[0] = *(const f4*)(op + coff); ro[1] = *(const f4*)(op + coff + HWp);
        }

        // ---- band MFMAs ----
        const short8 A = *reinterpret_cast<const short8*>(&smem[2193 + w * 65 + inn]);
        #pragma unroll
        for (int dy = 0; dy < 9; ++dy) {
            const short8 B0 = *reinterpret_cast<const short8*>(&smem[(w + dy) * 129 + inn]);
            acc0[dy] = __builtin_amdgcn_mfma_f32_16x16x32_bf16(A, B0, acc0[dy], 0, 0, 0);
        }
        #pragma unroll
        for (int p = 0; p < 5; ++p) {
            const short8 B1 = *reinterpret_cast<const short8*>(&smem[(w + 2 * p + nh) * 129 + in1]);
            acc1[p] = __builtin_amdgcn_mfma_f32_16x16x32_bf16(A, B1, acc1[p], 0, 0, 0);
        }
        __syncthreads();   // (B) reads done; next commit (or epilogue) may overwrite
    }

    // ---- epilogue: accs -> LDS (ep), then coalesced stores ----
    const float scale = 1.0f / (float)C_;
    #pragma unroll
    for (int dy = 0; dy < 9; ++dy) {
        floatx4 v = acc0[dy];
        #pragma unroll
        for (int r = 0; r < 4; ++r) {
            const int m  = 4 * q + r;
            const int dx = n - m;
            if ((unsigned)dx <= 8u)
                ep[((dy * 9 + dx) * 8 + w) * 16 + m] = v[r] * scale;
        }
    }
    #pragma unroll
    for (int p = 0; p < 5; ++p) {
        floatx4 v = acc1[p];
        const int dyy = 2 * p + nh;
        #pragma unroll
        for (int r = 0; r < 4; ++r) {
            const int m  = 4 * q + r;
            const int dx = 16 + (n & 7) - m;
            if ((unsigned)dx <= 8u && dyy <= 8)
                ep[((dyy * 9 + dx) * 8 + w) * 16 + m] = v[r] * scale;
        }
    }
    __syncthreads();
    #pragma unroll
    for (int i = 0; i < 21; ++i) {
        const int wid = i * 512 + tid;
        const int x   = wid & 15;
        const int y   = (wid >> 4) & 7;
        const int ch  = wid >> 7;
        if (ch < 81)
            out[((b * 81 + ch) * H_ + (y0 + y)) * W_ + (x0 + x)] = ep[(ch * 8 + y) * 16 + x];
    }
}

extern "C" void kernel_launch(void* const* d_in, const int* in_sizes, int n_in,
                              void* d_out, int out_size, void* d_ws, size_t ws_size,
                              hipStream_t stream) {
    const float* one = (const float*)d_in[0];
    const float* two = (const float*)d_in[1];
    float* out = (float*)d_out;
    corr_kernel<<<dim3(960), dim3(512), 0, stream>>>(one, two, out);
}

// Round 4
// 211.379 us; speedup vs baseline: 1.0137x; 1.0137x over previous
//
#include <hip/hip_runtime.h>

#define B_  8
#define C_  128
#define H_  96
#define W_  160
#define HWp (H_ * W_)   // 15360 floats per channel plane

typedef short  short8  __attribute__((ext_vector_type(8)));
typedef float  floatx4 __attribute__((ext_vector_type(4)));

// round-to-nearest-even fp32 -> bf16, packed pair (a low 16, b high 16)
__device__ __forceinline__ unsigned pk_bf16(float a, float b) {
    unsigned ua = __float_as_uint(a);
    unsigned ub = __float_as_uint(b);
    ua = (ua + 0x7FFFu + ((ua >> 16) & 1u)) >> 16;
    ub = (ub + 0x7FFFu + ((ub >> 16) & 1u)) & 0xFFFF0000u;
    return ua | ub;
}

// Band-GEMM correlation, dy-split waves:
//   out[b, dy*9+dx, y, x] = (1/128) * sum_c one[b,c,y,x] * two[b,c,y+dy-4,x+dx-4]
// Tile 4y x 16x, 1024 thr = 16 waves; wave = (yloc = w&3, part = w>>2).
//   part 0: ct0 dy 0..3 | part 1: ct0 dy 4..7 | part 2: ct0 dy8 + ct1 pp0,1 | part 3: ct1 pp2..4
// LDS records (16B = 8 bf16, k=q*8+j), XOR-by-q swizzle pos = nloc^q (write 2-way, read free).
//   twoQ[2]: 13 rows x 128 recs (rows 0..11 staged, 12 = junk for the dy=9 phantom)
//   oneQ[2]:  4 rows x  64 recs;  ep (epilogue, 81x4x17 fp32) unions over twoQ[0].
__global__ __launch_bounds__(1024, 4)
void corr_kernel(const float* __restrict__ one, const float* __restrict__ two,
                 float* __restrict__ out) {
    __shared__ uint4 smem[3840];     // 61,440 B: twoQ0@0, twoQ1@1664, oneQ0@3328, oneQ1@3584
    unsigned* sw = reinterpret_cast<unsigned*>(smem);
    float*    ep = reinterpret_cast<float*>(smem);

    const int id = blockIdx.x;
    const int b  = id & 7;            // one batch per XCD
    const int jj = id >> 3;
    const int yt = jj % 24;           // y fastest within XCD -> L2 halo reuse
    const int xt = jj / 24;
    const int y0 = yt * 4;
    const int x0 = xt * 16;

    const int tid  = threadIdx.x;
    const int lane = tid & 63;
    const int wv   = tid >> 6;
    const int yloc = wv & 3;
    const int part = wv >> 2;

    // ---- staging decode: c-pair tasks ----
    const int P    = tid & 15;        // c-pair index (c = c0 + 2P)
    const int xg   = (tid >> 4) & 7;  // x-quad
    const int rem  = tid >> 7;        // 0..7
    const int qq   = P >> 2;
    const int wsel = P & 3;
    const int ctc  = xg >> 2;
    const int nb   = 4 * (xg & 3);
    const int gxb  = x0 - 4 + 4 * xg;

    const int  ry0 = rem, ry1 = 8 + rem;
    const int  ty0 = y0 - 4 + ry0;
    const int  ty1 = y0 - 4 + ry1;
    const bool xv  = (gxb >= 0) && (gxb <= W_ - 4);
    const bool v0  = xv && ((unsigned)ty0 < H_);
    const bool hasT1 = (rem < 4);
    const bool v1  = hasT1 && xv && ((unsigned)ty1 < H_);

    const float* tp0 = two + ((b * C_ + 2 * P) * H_ + ty0) * W_ + gxb;
    const float* tp1 = two + ((b * C_ + 2 * P) * H_ + ty1) * W_ + gxb;

    // `one` staging owned by threads 512..767 (rem 4,5) to balance load counts
    const bool odo = (rem == 4) || (rem == 5);
    const int  u   = tid & 255;
    const int  oP  = u & 15;
    const int  oxg = (u >> 4) & 3;
    const int  oy  = u >> 6;
    const int  oqq = oP >> 2, owsel = oP & 3, onb = 4 * oxg;
    const float* op = one + ((b * C_ + 2 * oP) * H_ + (y0 + oy)) * W_ + (x0 + 4 * oxg);

    // commit bases in words (buffer 0); buffer 1 adds 6656 (two) / 1024 (one)
    const int t0b = (ry0 * 128 + ctc * 64 + qq * 16) * 4 + wsel;
    const int t1b = (ry1 * 128 + ctc * 64 + qq * 16) * 4 + wsel;
    const int o0b = (3328 + oy * 64 + oqq * 16) * 4 + owsel;

    // fragment-read offsets (record units)
    const int q   = lane >> 4;
    const int n   = lane & 15;
    const int nh  = n >> 3;
    const int in0 = q * 16 + (n ^ q);             // ct0 & A
    const int in1 = 64 + q * 16 + ((n & 7) ^ q);  // ct1

    floatx4 acc[4];
    #pragma unroll
    for (int i = 0; i < 4; ++i) acc[i] = floatx4{0.f, 0.f, 0.f, 0.f};

    floatx4 r0[2], r1[2], ro[2];
    auto do_loads = [&](int ck) {
        const int off = ck * 32 * HWp;
        if (v0) { r0[0] = *(const floatx4*)(tp0 + off); r0[1] = *(const floatx4*)(tp0 + off + HWp); }
        else    { r0[0] = floatx4{0.f,0.f,0.f,0.f}; r0[1] = floatx4{0.f,0.f,0.f,0.f}; }
        if (v1) { r1[0] = *(const floatx4*)(tp1 + off); r1[1] = *(const floatx4*)(tp1 + off + HWp); }
        else    { r1[0] = floatx4{0.f,0.f,0.f,0.f}; r1[1] = floatx4{0.f,0.f,0.f,0.f}; }
        if (odo){ ro[0] = *(const floatx4*)(op + off);  ro[1] = *(const floatx4*)(op + off + HWp); }
    };

    do_loads(0);

    #pragma unroll
    for (int ck = 0; ck < 4; ++ck) {
        const int bf   = ck & 1;
        const int twoW = bf * 6656;
        const int oneW = bf * 1024;

        // ---- commit raws -> LDS (b32, XOR-by-q swizzle: 2-way banks = free) ----
        #pragma unroll
        for (int j = 0; j < 4; ++j)
            sw[twoW + t0b + (((nb + j) ^ qq) << 2)] = pk_bf16(r0[0][j], r0[1][j]);
        if (hasT1) {
            #pragma unroll
            for (int j = 0; j < 4; ++j)
                sw[twoW + t1b + (((nb + j) ^ qq) << 2)] = pk_bf16(r1[0][j], r1[1][j]);
        }
        if (odo) {
            #pragma unroll
            for (int j = 0; j < 4; ++j)
                sw[oneW + o0b + (((onb + j) ^ oqq) << 2)] = pk_bf16(ro[0][j], ro[1][j]);
        }
        __syncthreads();   // staged data visible; single barrier per chunk (double-buffered)

        // ---- issue next chunk's loads (land during MFMA phase) ----
        if (ck < 3) do_loads(ck + 1);

        // ---- MFMA phase ----
        const uint4* twoB = smem + bf * 1664;
        const uint4* oneB = smem + 3328 + bf * 256;
        const short8 A = *reinterpret_cast<const short8*>(&oneB[yloc * 64 + in0]);
        if (part <= 1) {
            const int d0 = part * 4;
            #pragma unroll
            for (int i = 0; i < 4; ++i) {
                const short8 Bv = *reinterpret_cast<const short8*>(&twoB[(yloc + d0 + i) * 128 + in0]);
                acc[i] = __builtin_amdgcn_mfma_f32_16x16x32_bf16(A, Bv, acc[i], 0, 0, 0);
            }
        } else if (part == 2) {
            const short8 B0 = *reinterpret_cast<const short8*>(&twoB[(yloc + 8) * 128 + in0]);
            acc[0] = __builtin_amdgcn_mfma_f32_16x16x32_bf16(A, B0, acc[0], 0, 0, 0);
            #pragma unroll
            for (int ppi = 0; ppi < 2; ++ppi) {
                const short8 Bv = *reinterpret_cast<const short8*>(&twoB[(yloc + 2 * ppi + nh) * 128 + in1]);
                acc[1 + ppi] = __builtin_amdgcn_mfma_f32_16x16x32_bf16(A, Bv, acc[1 + ppi], 0, 0, 0);
            }
        } else {
            #pragma unroll
            for (int i = 0; i < 3; ++i) {
                const int pp = 2 + i;   // dy = 2*pp + nh (pp=4,nh=1 -> phantom row 12, discarded)
                const short8 Bv = *reinterpret_cast<const short8*>(&twoB[(yloc + 2 * pp + nh) * 128 + in1]);
                acc[i] = __builtin_amdgcn_mfma_f32_16x16x32_bf16(A, Bv, acc[i], 0, 0, 0);
            }
        }
    }

    // ---- epilogue scatter -> ep (aliases twoQ[0]; all buf0 reads retired at last barrier) ----
    const float scale = 1.0f / (float)C_;
    if (part <= 1) {
        #pragma unroll
        for (int i = 0; i < 4; ++i) {
            const int dy = part * 4 + i;
            #pragma unroll
            for (int r = 0; r < 4; ++r) {
                const int m = 4 * q + r;
                const int dx = n - m;
                if ((unsigned)dx <= 8u)
                    ep[((dy * 9 + dx) * 4 + yloc) * 17 + m] = acc[i][r] * scale;
            }
        }
    } else if (part == 2) {
        #pragma unroll
        for (int r = 0; r < 4; ++r) {
            const int m = 4 * q + r;
            const int dx = n - m;
            if ((unsigned)dx <= 8u)
                ep[((8 * 9 + dx) * 4 + yloc) * 17 + m] = acc[0][r] * scale;
        }
        #pragma unroll
        for (int ppi = 0; ppi < 2; ++ppi) {
            const int dy = 2 * ppi + nh;
            #pragma unroll
            for (int r = 0; r < 4; ++r) {
                const int m = 4 * q + r;
                const int dx = 16 + (n & 7) - m;
                if ((unsigned)dx <= 8u)
                    ep[((dy * 9 + dx) * 4 + yloc) * 17 + m] = acc[1 + ppi][r] * scale;
            }
        }
    } else {
        #pragma unroll
        for (int i = 0; i < 3; ++i) {
            const int dy = 2 * (2 + i) + nh;
            if (dy <= 8) {
                #pragma unroll
                for (int r = 0; r < 4; ++r) {
                    const int m = 4 * q + r;
                    const int dx = 16 + (n & 7) - m;
                    if ((unsigned)dx <= 8u)
                        ep[((dy * 9 + dx) * 4 + yloc) * 17 + m] = acc[i][r] * scale;
                }
            }
        }
    }
    __syncthreads();

    // ---- coalesced stores: 64B row segments ----
    #pragma unroll
    for (int i = 0; i < 6; ++i) {
        const int wid = i * 1024 + tid;
        const int x   = wid & 15;
        const int yy  = (wid >> 4) & 3;
        const int ch  = wid >> 6;
        if (ch < 81)
            out[((b * 81 + ch) * H_ + (y0 + yy)) * W_ + (x0 + x)] = ep[(ch * 4 + yy) * 17 + x];
    }
}

extern "C" void kernel_launch(void* const* d_in, const int* in_sizes, int n_in,
                              void* d_out, int out_size, void* d_ws, size_t ws_size,
                              hipStream_t stream) {
    const float* one = (const float*)d_in[0];
    const float* two = (const float*)d_in[1];
    float* out = (float*)d_out;
    // grid: 8 batches * 24 y-tiles * 10 x-tiles = 1920 blocks of 1024 threads
    corr_kernel<<<dim3(1920), dim3(1024), 0, stream>>>(one, two, out);
}